// Round 14
// baseline (379.403 us; speedup 1.0000x reference)
//
#include <hip/hip_runtime.h>
#include <cmath>

typedef unsigned short u16;
typedef __attribute__((ext_vector_type(8))) short bf16x8;
typedef __attribute__((ext_vector_type(4))) float f32x4;

#define TT 2048
#define CC 1024
#define BT 8192   // B*T

__device__ __forceinline__ float fexp2(float x) {
  return __builtin_amdgcn_exp2f(x);   // v_exp_f32 (HW exp2)
}

__device__ __forceinline__ u16 f2bf(float f) {
  unsigned u = __builtin_bit_cast(unsigned, f);
  u += 0x7fffu + ((u >> 16) & 1u);
  return (u16)(u >> 16);
}

__device__ __forceinline__ float bf2f(u16 u) {
  return __builtin_bit_cast(float, (unsigned)u << 16);
}

__device__ __forceinline__ float gelu_tanh(float v) {
  // 0.5v(1+tanh(0.79788456(v+0.044715v^3))) = v*sigmoid(1.59576912v+0.07135482v^3)
  float u2 = v * (1.595769122f + 0.071354816f * v * v);
  return v / (1.f + __expf(-u2));
}

__device__ __forceinline__ void gload_lds16(const void* g, void* l) {
  __builtin_amdgcn_global_load_lds(
      (const __attribute__((address_space(1))) void*)g,
      (__attribute__((address_space(3))) void*)l, 16, 0, 0);
}

// ---------------- weight prep ----------------

// 4 x 1M-element f32->bf16 converts in one launch (dst segments contiguous)
__global__ __launch_bounds__(256) void cvt4_kernel(const float* __restrict__ s0,
                                                   const float* __restrict__ s1,
                                                   const float* __restrict__ s2,
                                                   const float* __restrict__ s3,
                                                   u16* __restrict__ d) {
  int blk = blockIdx.x;           // 0..4095
  int seg = blk >> 10;
  const float* s = (seg == 0) ? s0 : (seg == 1) ? s1 : (seg == 2) ? s2 : s3;
  int i = ((blk & 1023) * 256 + threadIdx.x) * 4;
  float4 v = *(const float4*)(s + i);
  ushort4 o;
  o.x = f2bf(v.x); o.y = f2bf(v.y); o.z = f2bf(v.z); o.w = f2bf(v.w);
  *(ushort4*)(d + (seg << 20) + i) = o;
}

// src [R][C] f32 -> dst [C][R] bf16 ; R,C multiples of 32
__global__ __launch_bounds__(256) void transpose_cvt(const float* __restrict__ src,
                                                     u16* __restrict__ dst,
                                                     int R, int C) {
  __shared__ float tile[32][33];
  int c0 = blockIdx.x * 32, r0 = blockIdx.y * 32;
  int tx = threadIdx.x, ty = threadIdx.y;
#pragma unroll
  for (int j = 0; j < 4; ++j)
    tile[ty + j * 8][tx] = src[(size_t)(r0 + ty + j * 8) * C + c0 + tx];
  __syncthreads();
#pragma unroll
  for (int j = 0; j < 4; ++j)
    dst[(size_t)(c0 + ty + j * 8) * R + r0 + tx] = f2bf(tile[tx][ty + j * 8]);
}

// ---------------- layernorm (f32 in -> bf16 out) ----------------

__global__ __launch_bounds__(256) void ln_kernel(const float* __restrict__ x,
                                                 const float* __restrict__ gw,
                                                 const float* __restrict__ bw,
                                                 u16* __restrict__ out) {
  int row = blockIdx.x;
  int tid = threadIdx.x;
  const size_t base = (size_t)row * CC;
  float4 v = *(const float4*)(x + base + tid * 4);
  float s = v.x + v.y + v.z + v.w;
  float q = v.x * v.x + v.y * v.y + v.z * v.z + v.w * v.w;
#pragma unroll
  for (int o = 32; o > 0; o >>= 1) {
    s += __shfl_down(s, o, 64);
    q += __shfl_down(q, o, 64);
  }
  __shared__ float red[8];
  __shared__ float stat[2];
  int lane = tid & 63, wid = tid >> 6;
  if (!lane) { red[wid] = s; red[4 + wid] = q; }
  __syncthreads();
  if (!tid) {
    float S = red[0] + red[1] + red[2] + red[3];
    float Q = red[4] + red[5] + red[6] + red[7];
    float mu = S * (1.0f / CC);
    float var = Q * (1.0f / CC) - mu * mu;
    stat[0] = mu;
    stat[1] = rsqrtf(var + 1e-5f);
  }
  __syncthreads();
  float mu = stat[0], rs = stat[1];
  int c = tid * 4;
  float4 gv = *(const float4*)(gw + c);
  float4 bv = *(const float4*)(bw + c);
  ushort4 o;
  o.x = f2bf((v.x - mu) * rs * gv.x + bv.x);
  o.y = f2bf((v.y - mu) * rs * gv.y + bv.y);
  o.z = f2bf((v.z - mu) * rs * gv.z + bv.z);
  o.w = f2bf((v.w - mu) * rs * gv.w + bv.w);
  *(ushort4*)(out + base + c) = o;
}

// ---------------- split-K reduce: d_out = p0 + p1 + bias + resid (f32) --------

__global__ __launch_bounds__(256) void rf2_kernel(const u16* __restrict__ p0,
                                                  const u16* __restrict__ p1,
                                                  const float* __restrict__ b2,
                                                  const float* __restrict__ resid,
                                                  float* __restrict__ out) {
  int c = threadIdx.x * 4;
  size_t i = (size_t)blockIdx.x * CC + c;
  ushort4 a = *(const ushort4*)(p0 + i);
  ushort4 b = *(const ushort4*)(p1 + i);
  float4 r = *(const float4*)(resid + i);
  float4 bb = *(const float4*)(b2 + c);
  float4 o;
  o.x = bf2f(a.x) + bf2f(b.x) + r.x + bb.x;
  o.y = bf2f(a.y) + bf2f(b.y) + r.y + bb.y;
  o.z = bf2f(a.z) + bf2f(b.z) + r.z + bb.z;
  o.w = bf2f(a.w) + bf2f(b.w) + r.w + bb.w;
  *(float4*)(out + i) = o;
}

// ---------------- GEMM 128x128 (m97 structure), Wo: C = A*B^T + resid -> f32 --
// 512 blocks of 16KB LDS -> ~3 blocks/CU (latency-hiding TLP regime).

__global__ __launch_bounds__(256) void gemm_bt(const u16* __restrict__ A,
                                               const u16* __restrict__ B,
                                               float* __restrict__ Cv,
                                               const float* __restrict__ resid,
                                               int N, int K) {
  __shared__ u16 As[4096];  // [128][32]
  __shared__ u16 Bs[4096];  // [128][32]
  const int tid = threadIdx.x, lane = tid & 63, wid = tid >> 6;
  const int tM = blockIdx.x * 128, tN = blockIdx.y * 128;
  const int wr = wid >> 1, wc = wid & 1;
  const int lr = lane >> 2, lc = (lane & 3) * 8;
  const int fr = lane & 15, fo = (lane >> 4) * 8;
  f32x4 acc[4][4] = {};
  const u16* Ab = A + (size_t)tM * K;
  const u16* Bb = B + (size_t)tN * K;
  for (int k0 = 0; k0 < K; k0 += 32) {
#pragma unroll
    for (int i = 0; i < 2; ++i) {
      int seg = wid * 2 + i;
      int row = seg * 16 + lr;
      gload_lds16(Ab + (size_t)row * K + k0 + lc, &As[seg * 512]);
      gload_lds16(Bb + (size_t)row * K + k0 + lc, &Bs[seg * 512]);
    }
    __syncthreads();
    bf16x8 af[4], bfr[4];
#pragma unroll
    for (int mi = 0; mi < 4; ++mi)
      af[mi] = *(const bf16x8*)&As[(wr * 64 + mi * 16 + fr) * 32 + fo];
#pragma unroll
    for (int ni = 0; ni < 4; ++ni)
      bfr[ni] = *(const bf16x8*)&Bs[(wc * 64 + ni * 16 + fr) * 32 + fo];
#pragma unroll
    for (int mi = 0; mi < 4; ++mi)
#pragma unroll
      for (int ni = 0; ni < 4; ++ni)
        acc[mi][ni] = __builtin_amdgcn_mfma_f32_16x16x32_bf16(af[mi], bfr[ni],
                                                              acc[mi][ni], 0, 0, 0);
    __syncthreads();
  }
  const int fq = lane >> 4;
#pragma unroll
  for (int mi = 0; mi < 4; ++mi) {
#pragma unroll
    for (int ni = 0; ni < 4; ++ni) {
      const int gR0 = tM + wr * 64 + mi * 16 + fq * 4;
      const int gC = tN + wc * 64 + ni * 16 + fr;
#pragma unroll
      for (int r = 0; r < 4; ++r) {
        size_t idx = (size_t)(gR0 + r) * N + gC;
        Cv[idx] = acc[mi][ni][r] + resid[idx];
      }
    }
  }
}

// ---------------- GEMM 256x256, 8-phase counted-vmcnt (m201 template) ----------
// C[M,N] = A[M,K-slice] * B[N,K-slice]^T ; row stride Kst, loop extent K.
// kslice = sb/kdiv selects K-window [kslice*K, (kslice+1)*K) and partial buffer.
// PERS: grid is halved; each block runs TWO complete, independent pipelines for
//       M-adjacent tiles (2*m2, n) then (2*m2+1, n) — same B-panel (L2-hot 2nd
//       fill). Every loop-internal wait is identical to the non-PERS kernel.
// EPI: 0 = bf16 store to (kslice ? vt : Cv)
//      2 = +bias, GELU -> bf16 | 4 = QKV epilogue (Q*0.125*log2e, K, V->VT)

template <int EPI, bool PERS>
__global__ __launch_bounds__(512) void gemm256(const u16* __restrict__ A,
                                               const u16* __restrict__ B,
                                               void* __restrict__ Cv,
                                               const float* __restrict__ bias,
                                               const float* __restrict__ resid,
                                               u16* __restrict__ vt,
                                               int N, int K, int Kst,
                                               int gn, int kdiv) {
  __shared__ u16 lds[8][8192];  // 8 slots x 16KB, each a [256][32] bf16 half-tile
  const int tid = threadIdx.x, lane = tid & 63, wid = tid >> 6;
  const int nwg = gridDim.x;
  const int bid = blockIdx.x;
  const int sb = (nwg & 7) ? bid : ((bid & 7) * (nwg >> 3) + (bid >> 3));
  const int kslice = PERS ? 0 : (sb / kdiv);
  const int rem = PERS ? sb : (sb % kdiv);
  const int tM0 = PERS ? ((rem / gn) * 512) : ((rem / gn) * 256);
  const int tN = (rem % gn) * 256;
  const int wm = wid >> 2, wn = wid & 3;          // 2M x 4N waves
  const int fr = lane & 15, g4 = lane >> 4;       // frag row / k-group
  const int gsw = (g4 ^ ((fr >> 3) << 1)) * 8;    // st_16x32 swizzled k-offset
  const int srow0 = wid * 16 + (lane >> 2);       // staging row (+ i*128)
  const int scol = ((lane & 3) ^ ((lane >> 5) << 1)) * 8;  // inverse-swizzled src col
  const u16* pB = B + (size_t)kslice * K + (size_t)tN * Kst + (size_t)srow0 * Kst + scol;
  const int NKT = K >> 6;
  const int NH = PERS ? 2 : 1;

  for (int half = 0; half < NH; ++half) {
    const int tM = tM0 + half * 256;
    const u16* pA = A + (size_t)kslice * K + (size_t)tM * Kst +
                    (size_t)srow0 * Kst + scol;
    f32x4 acc[8][4] = {};

    auto stage = [&](int idx) {
      int kof = (idx >> 1) << 5;                  // = ts*64 + (half k)*32
      const u16* G = (idx & 1) ? pB : pA;
      u16* dst = &lds[idx & 7][wid * 512];
      gload_lds16(G + kof, dst);
      gload_lds16(G + (size_t)128 * Kst + kof, dst + 4096);
    };

    // prologue: 4 halves, vmcnt(4), 3 halves, vmcnt(6) (3 half-tiles in flight)
#pragma unroll
    for (int j = 0; j < 4; ++j) stage(j);
    asm volatile("s_waitcnt vmcnt(4)" ::: "memory");
#pragma unroll
    for (int j = 4; j < 7; ++j) stage(j);
    asm volatile("s_waitcnt vmcnt(6)" ::: "memory");
    __builtin_amdgcn_s_barrier();

    for (int t2 = 0; t2 < NKT; t2 += 2) {
#pragma unroll
      for (int tt = 0; tt < 2; ++tt) {
        const int t = t2 + tt;
        const int bo = tt << 2;                   // compile-time slot base
#pragma unroll
        for (int ks = 0; ks < 2; ++ks) {
          const u16* Ah = lds[bo | (ks << 1)];
          const u16* Bh = lds[bo | (ks << 1) | 1];
          bf16x8 bfr[4];
#pragma unroll
          for (int ni = 0; ni < 4; ++ni)
            bfr[ni] = *(const bf16x8*)&Bh[(wn * 64 + ni * 16 + fr) * 32 + gsw];
#pragma unroll
          for (int mh = 0; mh < 2; ++mh) {
            bf16x8 af[4];
#pragma unroll
            for (int mi = 0; mi < 4; ++mi)
              af[mi] = *(const bf16x8*)&Ah[(wm * 128 + mh * 64 + mi * 16 + fr) * 32 + gsw];
            __builtin_amdgcn_sched_barrier(0);
            int idx = 4 * t + (ks << 1) + mh + 7; // stage 7 phases ahead
            if (idx < 4 * NKT) stage(idx);
            __builtin_amdgcn_s_barrier();
            asm volatile("s_waitcnt lgkmcnt(0)" ::: "memory");
            __builtin_amdgcn_sched_barrier(0);
            __builtin_amdgcn_s_setprio(1);
#pragma unroll
            for (int mi = 0; mi < 4; ++mi)
#pragma unroll
              for (int ni = 0; ni < 4; ++ni)
                acc[mh * 4 + mi][ni] = __builtin_amdgcn_mfma_f32_16x16x32_bf16(
                    af[mi], bfr[ni], acc[mh * 4 + mi][ni], 0, 0, 0);
            __builtin_amdgcn_s_setprio(0);
            __builtin_amdgcn_sched_barrier(0);
            if (ks == 1 && mh == 1) {             // once per K-tile
              if (t < NKT - 2) asm volatile("s_waitcnt vmcnt(6)" ::: "memory");
              else if (t == NKT - 2) asm volatile("s_waitcnt vmcnt(0)" ::: "memory");
            }
            __builtin_amdgcn_s_barrier();
          }
        }
      }
    }

#pragma unroll
    for (int m = 0; m < 8; ++m) {
#pragma unroll
      for (int ni = 0; ni < 4; ++ni) {
        const int gR0 = tM + wm * 128 + m * 16 + g4 * 4;
        const int gC = tN + wn * 64 + ni * 16 + fr;
        if constexpr (EPI == 4) {
          if (gC < 2048) {
            // Q scaled by D^-0.5 * log2(e) so attn softmax runs in exp2 domain
            float sc = (gC < 1024) ? 0.180336884f : 1.0f;
#pragma unroll
            for (int r = 0; r < 4; ++r)
              ((u16*)Cv)[(size_t)(gR0 + r) * 3072 + gC] = f2bf(acc[m][ni][r] * sc);
          } else {
            int tr = gR0 & 2047, bb = gR0 >> 11;
            int dv = gC - 2048, hh = dv >> 6, dd = dv & 63;
            int k5 = tr & 31;  // multiple of 4
            int pos = ((k5 & 15) >> 2) * 8 + ((k5 >> 4) & 1) * 4;
            ushort4 q4;
            q4.x = f2bf(acc[m][ni][0]);
            q4.y = f2bf(acc[m][ni][1]);
            q4.z = f2bf(acc[m][ni][2]);
            q4.w = f2bf(acc[m][ni][3]);
            *(ushort4*)&vt[((size_t)((bb * 16 + hh) * 64 + dd)) * 2048 + (tr & ~31) + pos] = q4;
          }
        } else if constexpr (EPI == 0) {
          u16* dst = kslice ? vt : (u16*)Cv;
#pragma unroll
          for (int r = 0; r < 4; ++r)
            dst[(size_t)(gR0 + r) * N + gC] = f2bf(acc[m][ni][r]);
        } else {
#pragma unroll
          for (int r = 0; r < 4; ++r) {
            float v = gelu_tanh(acc[m][ni][r] + bias[gC]);
            ((u16*)Cv)[(size_t)(gR0 + r) * N + gC] = f2bf(v);
          }
        }
      }
    }
  }
}

// ---------------- causal flash attention (swapped-QK^T, in-register P) ----------------
// Q pre-scaled by 0.125*log2e -> softmax in exp2 domain. 1D grid, XCD-chunked.
// Double-buffered K/V with COUNTED vmcnt(4) + raw barriers (no per-tile full
// drain): each wave's stage() = exactly 4 global_load_lds.

__global__ __launch_bounds__(256) void attn_kernel(const u16* __restrict__ qkv,
                                                   const u16* __restrict__ vt,
                                                   u16* __restrict__ out) {
  const int bid = blockIdx.x;
  const int sb = (bid & 7) * 128 + (bid >> 3);   // XCD-chunked remap (1024 blocks)
  const int pair = sb & 15;
  const int bh = sb >> 4;
  const int b = bh >> 4, h = bh & 15;
  const int tid = threadIdx.x, lane = tid & 63, wid = tid >> 6;
  const int ql = lane & 15, g = lane >> 4;
  const int sw = ql & 7;              // read-side swizzle key
  __shared__ u16 Ks[2][4096];         // [64 keys][64 d], XOR-swizzled chunks
  __shared__ u16 Vs[2][4096];         // [64 d][64 keys permuted], XOR-swizzled
  const size_t rowQbase = (size_t)b * TT;
  const u16* kpart = qkv + rowQbase * 3072 + 1024 + h * 64;
  const u16* vpart = vt + ((size_t)(b * 16 + h) * 64) * 2048;
  const int srow = lane >> 3;
  const int sc16 = lane & 7;

  for (int pass = 0; pass < 2; ++pass) {
    const int qt = pass ? (31 - pair) : pair;
    const int qrow0 = qt * 64 + wid * 16;
    const int q_glb = qrow0 + ql;
    const u16* qp = qkv + (rowQbase + q_glb) * 3072 + h * 64 + g * 8;
    bf16x8 qf0 = *(const bf16x8*)qp;
    bf16x8 qf1 = *(const bf16x8*)(qp + 32);
    f32x4 o[4] = {};
    float m_run = -1e30f, l_run = 0.f;
    const int nt = qt + 1;

    auto stage = [&](int bufi, int t) {
      int kv0 = t * 64;
#pragma unroll
      for (int i = 0; i < 2; ++i) {
        int seg = wid * 2 + i;
        int rloc = seg * 8 + srow;
        int cs = (sc16 ^ (rloc & 7)) * 8;
        gload_lds16(kpart + (size_t)(kv0 + rloc) * 3072 + cs, &Ks[bufi][seg * 512]);
        gload_lds16(vpart + (size_t)rloc * 2048 + kv0 + cs, &Vs[bufi][seg * 512]);
      }
    };

    stage(0, 0);
    __syncthreads();
    int buf = 0;
    for (int t = 0; t < nt; ++t) {
      // prefetch next tile, then wait only for CURRENT buffer's 4 loads
      if (t + 1 < nt) {
        stage(buf ^ 1, t + 1);
        asm volatile("s_waitcnt vmcnt(4)" ::: "memory");
      } else {
        asm volatile("s_waitcnt vmcnt(0)" ::: "memory");
      }
      __builtin_amdgcn_s_barrier();       // all waves: buf resident in LDS
      __builtin_amdgcn_sched_barrier(0);
      const u16* Kb = Ks[buf];
      const u16* Vb = Vs[buf];
      const int kv0 = t * 64;
      float p[16];
      __builtin_amdgcn_s_setprio(1);
#pragma unroll
      for (int kt = 0; kt < 4; ++kt) {
        int row = kt * 16 + ql;
        bf16x8 k0 = *(const bf16x8*)&Kb[row * 64 + ((g ^ sw) * 8)];
        bf16x8 k1 = *(const bf16x8*)&Kb[row * 64 + (((4 + g) ^ sw) * 8)];
        f32x4 s = {0.f, 0.f, 0.f, 0.f};
        s = __builtin_amdgcn_mfma_f32_16x16x32_bf16(k0, qf0, s, 0, 0, 0);
        s = __builtin_amdgcn_mfma_f32_16x16x32_bf16(k1, qf1, s, 0, 0, 0);
        if (t == qt) {
#pragma unroll
          for (int r = 0; r < 4; ++r) {
            int k_glb = kv0 + kt * 16 + 4 * g + r;
            p[kt * 4 + r] = (k_glb <= q_glb) ? s[r] : -1e30f;
          }
        } else {
#pragma unroll
          for (int r = 0; r < 4; ++r) p[kt * 4 + r] = s[r];
        }
      }
      __builtin_amdgcn_s_setprio(0);
      // ---- online softmax (exp2 domain), tree reductions ----
      float t8[8];
#pragma unroll
      for (int i = 0; i < 8; ++i) t8[i] = fmaxf(p[i], p[i + 8]);
#pragma unroll
      for (int i = 0; i < 4; ++i) t8[i] = fmaxf(t8[i], t8[i + 4]);
      float mloc = fmaxf(fmaxf(t8[0], t8[1]), fmaxf(t8[2], t8[3]));
      mloc = fmaxf(mloc, __shfl_xor(mloc, 16));
      mloc = fmaxf(mloc, __shfl_xor(mloc, 32));
      if (!__all(mloc <= m_run + 8.f)) {         // defer-max: P bounded by 2^8
        float mnew = fmaxf(m_run, mloc);
        float alpha = fexp2(m_run - mnew);
        m_run = mnew;
        l_run *= alpha;
        float aO[4];
#pragma unroll
        for (int r = 0; r < 4; ++r) aO[r] = __shfl(alpha, 4 * g + r);
#pragma unroll
        for (int d0 = 0; d0 < 4; ++d0)
#pragma unroll
          for (int r = 0; r < 4; ++r) o[d0][r] *= aO[r];
      }
      float e[16];
#pragma unroll
      for (int i = 0; i < 16; ++i) e[i] = fexp2(p[i] - m_run);
      float s8[8];
#pragma unroll
      for (int i = 0; i < 8; ++i) s8[i] = e[i] + e[i + 8];
#pragma unroll
      for (int i = 0; i < 4; ++i) s8[i] += s8[i + 4];
      float lloc = (s8[0] + s8[1]) + (s8[2] + s8[3]);
      lloc += __shfl_xor(lloc, 16);
      lloc += __shfl_xor(lloc, 32);
      l_run += lloc;
      // pack P -> bf16 via v_cvt_pk_bf16_f32 (RNE), 8 insts for 16 values
      int4 w0, w1;
      asm("v_cvt_pk_bf16_f32 %0, %1, %2" : "=v"(w0.x) : "v"(e[0]), "v"(e[1]));
      asm("v_cvt_pk_bf16_f32 %0, %1, %2" : "=v"(w0.y) : "v"(e[2]), "v"(e[3]));
      asm("v_cvt_pk_bf16_f32 %0, %1, %2" : "=v"(w0.z) : "v"(e[4]), "v"(e[5]));
      asm("v_cvt_pk_bf16_f32 %0, %1, %2" : "=v"(w0.w) : "v"(e[6]), "v"(e[7]));
      asm("v_cvt_pk_bf16_f32 %0, %1, %2" : "=v"(w1.x) : "v"(e[8]), "v"(e[9]));
      asm("v_cvt_pk_bf16_f32 %0, %1, %2" : "=v"(w1.y) : "v"(e[10]), "v"(e[11]));
      asm("v_cvt_pk_bf16_f32 %0, %1, %2" : "=v"(w1.z) : "v"(e[12]), "v"(e[13]));
      asm("v_cvt_pk_bf16_f32 %0, %1, %2" : "=v"(w1.w) : "v"(e[14]), "v"(e[15]));
      bf16x8 pa0 = __builtin_bit_cast(bf16x8, w0);
      bf16x8 pa1 = __builtin_bit_cast(bf16x8, w1);
      __builtin_amdgcn_s_setprio(1);
#pragma unroll
      for (int d0 = 0; d0 < 4; ++d0) {
        int row = d0 * 16 + ql;
        bf16x8 v0 = *(const bf16x8*)&Vb[row * 64 + ((g ^ sw) * 8)];
        bf16x8 v1 = *(const bf16x8*)&Vb[row * 64 + (((4 + g) ^ sw) * 8)];
        o[d0] = __builtin_amdgcn_mfma_f32_16x16x32_bf16(pa0, v0, o[d0], 0, 0, 0);
        o[d0] = __builtin_amdgcn_mfma_f32_16x16x32_bf16(pa1, v1, o[d0], 0, 0, 0);
      }
      __builtin_amdgcn_s_setprio(0);
      __builtin_amdgcn_s_barrier();       // reads of buf done before overwrite
      buf ^= 1;
    }
    float linv = 1.0f / l_run;
    float lO[4];
#pragma unroll
    for (int r = 0; r < 4; ++r) lO[r] = __shfl(linv, 4 * g + r);
#pragma unroll
    for (int d0 = 0; d0 < 4; ++d0) {
#pragma unroll
      for (int r = 0; r < 4; ++r) {
        size_t idx = (rowQbase + qrow0 + 4 * g + r) * CC + h * 64 + d0 * 16 + ql;
        out[idx] = f2bf(o[d0][r] * lO[r]);
      }
    }
  }
}

// ---------------- launch ----------------

extern "C" void kernel_launch(void* const* d_in, const int* in_sizes, int n_in,
                              void* d_out, int out_size, void* d_ws, size_t ws_size,
                              hipStream_t stream) {
  const float* x   = (const float*)d_in[0];
  const float* Wq  = (const float*)d_in[1];
  const float* Wk  = (const float*)d_in[2];
  const float* Wv  = (const float*)d_in[3];
  const float* Wo  = (const float*)d_in[4];
  const float* W1  = (const float*)d_in[5];
  const float* b1  = (const float*)d_in[6];
  const float* W2  = (const float*)d_in[7];
  const float* b2  = (const float*)d_in[8];
  const float* g1  = (const float*)d_in[9];
  const float* be1 = (const float*)d_in[10];
  const float* g2  = (const float*)d_in[11];
  const float* be2 = (const float*)d_in[12];

  char* ws = (char*)d_ws;
  size_t off = 0;
  u16* Wqkv = (u16*)(ws + off); off += (size_t)3072 * 1024 * 2;
  u16* Wob  = (u16*)(ws + off); off += (size_t)1024 * 1024 * 2;
  u16* W1T  = (u16*)(ws + off); off += (size_t)4096 * 1024 * 2;
  u16* W2T  = (u16*)(ws + off); off += (size_t)1024 * 4096 * 2;
  u16* Hb   = (u16*)(ws + off); off += (size_t)BT * 1024 * 2;
  u16* QKV  = (u16*)(ws + off); off += (size_t)BT * 3072 * 2;
  u16* AttO = (u16*)(ws + off); off += (size_t)BT * 1024 * 2;
  float* X2 = (float*)(ws + off); off += (size_t)BT * 1024 * 4;
  u16* FF1 = QKV;        // [8192][4096] overlays QKV+AttO exactly (both dead by then)
  u16* VT  = (u16*)X2;   // 16.8MB <= 32MB; dead before X2 is written (Wo GEMM)
  if (ws_size < off) return;
  const int KBIG = 1 << 20;  // kdiv for non-split calls

  cvt4_kernel<<<4096, 256, 0, stream>>>(Wq, Wk, Wv, Wo, Wqkv);
  transpose_cvt<<<dim3(128, 32), dim3(32, 8), 0, stream>>>(W1, W1T, 1024, 4096);
  transpose_cvt<<<dim3(32, 128), dim3(32, 8), 0, stream>>>(W2, W2T, 4096, 1024);

  ln_kernel<<<BT, 256, 0, stream>>>(x, g1, be1, Hb);
  gemm256<4, false><<<32 * 12, 512, 0, stream>>>(Hb, Wqkv, QKV, nullptr, nullptr, VT,
                                                 3072, 1024, 1024, 12, KBIG);
  attn_kernel<<<1024, 256, 0, stream>>>(QKV, VT, AttO);
  // Wo: m97 128^2 structure, 512 blocks (~3 blocks/CU TLP), proven in R3
  gemm_bt<<<dim3(64, 8), 256, 0, stream>>>(AttO, Wob, X2, x, 1024, 1024);
  ln_kernel<<<BT, 256, 0, stream>>>(X2, g2, be2, Hb);
  // FF1: persistent M-paired blocks (2 full pipelines, shared B-panel), grid 256
  gemm256<2, true><<<256, 512, 0, stream>>>(Hb, W1T, FF1, b1, nullptr, nullptr,
                                            4096, 1024, 1024, 16, KBIG);
  // FF2 split-K x2: full-chip grid 256; bf16 partials into dead Hb/AttO
  gemm256<0, false><<<32 * 8, 512, 0, stream>>>(FF1, W2T, Hb, nullptr, nullptr, AttO,
                                                1024, 2048, 4096, 4, 128);
  rf2_kernel<<<BT, 256, 0, stream>>>(Hb, AttO, b2, X2, (float*)d_out);
}

// Round 15
// 372.616 us; speedup vs baseline: 1.0182x; 1.0182x over previous
//
#include <hip/hip_runtime.h>
#include <cmath>

typedef unsigned short u16;
typedef __attribute__((ext_vector_type(8))) short bf16x8;
typedef __attribute__((ext_vector_type(4))) float f32x4;

#define TT 2048
#define CC 1024
#define BT 8192   // B*T

__device__ __forceinline__ float fexp2(float x) {
  return __builtin_amdgcn_exp2f(x);   // v_exp_f32 (HW exp2)
}

__device__ __forceinline__ u16 f2bf(float f) {
  unsigned u = __builtin_bit_cast(unsigned, f);
  u += 0x7fffu + ((u >> 16) & 1u);
  return (u16)(u >> 16);
}

__device__ __forceinline__ float bf2f(u16 u) {
  return __builtin_bit_cast(float, (unsigned)u << 16);
}

__device__ __forceinline__ float gelu_tanh(float v) {
  // 0.5v(1+tanh(0.79788456(v+0.044715v^3))) = v*sigmoid(1.59576912v+0.07135482v^3)
  float u2 = v * (1.595769122f + 0.071354816f * v * v);
  return v / (1.f + __expf(-u2));
}

__device__ __forceinline__ void gload_lds16(const void* g, void* l) {
  __builtin_amdgcn_global_load_lds(
      (const __attribute__((address_space(1))) void*)g,
      (__attribute__((address_space(3))) void*)l, 16, 0, 0);
}

// ---------------- fused prep: weight cvt + 2 transposes + LN1 (one launch) ----
// blocks [0,4096):    Wq/Wk/Wv/Wo f32->bf16 into Wqkv (contiguous segments)
// blocks [4096,8192): W1 [1024][4096] -> W1T [4096][1024] bf16
// blocks [8192,12288):W2 [4096][1024] -> W2T [1024][4096] bf16
// blocks [12288,20480): LN1 row -> Hb bf16

__global__ __launch_bounds__(256) void prep_kernel(
    const float* __restrict__ Wq, const float* __restrict__ Wk,
    const float* __restrict__ Wv, const float* __restrict__ Wo,
    const float* __restrict__ W1, const float* __restrict__ W2,
    const float* __restrict__ x,  const float* __restrict__ g1,
    const float* __restrict__ be1,
    u16* __restrict__ Wqkv, u16* __restrict__ W1T, u16* __restrict__ W2T,
    u16* __restrict__ Hb) {
  const int blk = blockIdx.x;
  const int tid = threadIdx.x;
  if (blk < 4096) {                      // ---- cvt4 ----
    int seg = blk >> 10;
    const float* s = (seg == 0) ? Wq : (seg == 1) ? Wk : (seg == 2) ? Wv : Wo;
    int i = ((blk & 1023) * 256 + tid) * 4;
    float4 v = *(const float4*)(s + i);
    ushort4 o;
    o.x = f2bf(v.x); o.y = f2bf(v.y); o.z = f2bf(v.z); o.w = f2bf(v.w);
    *(ushort4*)(Wqkv + (seg << 20) + i) = o;
  } else if (blk < 12288) {              // ---- transpose_cvt ----
    __shared__ float tile[32][33];
    const bool w1 = blk < 8192;
    const int idx = blk - (w1 ? 4096 : 8192);
    const float* src = w1 ? W1 : W2;
    u16* dst = w1 ? W1T : W2T;
    const int R = w1 ? 1024 : 4096, C = w1 ? 4096 : 1024;
    const int c0 = (w1 ? (idx & 127) : (idx & 31)) * 32;
    const int r0 = (w1 ? (idx >> 7) : (idx >> 5)) * 32;
    const int tx = tid & 31, ty = tid >> 5;
#pragma unroll
    for (int j = 0; j < 4; ++j)
      tile[ty + j * 8][tx] = src[(size_t)(r0 + ty + j * 8) * C + c0 + tx];
    __syncthreads();
#pragma unroll
    for (int j = 0; j < 4; ++j)
      dst[(size_t)(c0 + ty + j * 8) * R + r0 + tx] = f2bf(tile[tx][ty + j * 8]);
  } else {                               // ---- LN1 ----
    __shared__ float red[8];
    __shared__ float stat[2];
    const int row = blk - 12288;
    const size_t base = (size_t)row * CC;
    float4 v = *(const float4*)(x + base + tid * 4);
    float s = v.x + v.y + v.z + v.w;
    float q = v.x * v.x + v.y * v.y + v.z * v.z + v.w * v.w;
#pragma unroll
    for (int o = 32; o > 0; o >>= 1) {
      s += __shfl_down(s, o, 64);
      q += __shfl_down(q, o, 64);
    }
    int lane = tid & 63, wid = tid >> 6;
    if (!lane) { red[wid] = s; red[4 + wid] = q; }
    __syncthreads();
    if (!tid) {
      float S = red[0] + red[1] + red[2] + red[3];
      float Q = red[4] + red[5] + red[6] + red[7];
      float mu = S * (1.0f / CC);
      float var = Q * (1.0f / CC) - mu * mu;
      stat[0] = mu;
      stat[1] = rsqrtf(var + 1e-5f);
    }
    __syncthreads();
    float mu = stat[0], rs = stat[1];
    int c = tid * 4;
    float4 gv = *(const float4*)(g1 + c);
    float4 bv = *(const float4*)(be1 + c);
    ushort4 o;
    o.x = f2bf((v.x - mu) * rs * gv.x + bv.x);
    o.y = f2bf((v.y - mu) * rs * gv.y + bv.y);
    o.z = f2bf((v.z - mu) * rs * gv.z + bv.z);
    o.w = f2bf((v.w - mu) * rs * gv.w + bv.w);
    *(ushort4*)(Hb + base + c) = o;
  }
}

// ---------------- layernorm (f32 in -> bf16 out) ----------------

__global__ __launch_bounds__(256) void ln_kernel(const float* __restrict__ x,
                                                 const float* __restrict__ gw,
                                                 const float* __restrict__ bw,
                                                 u16* __restrict__ out) {
  int row = blockIdx.x;
  int tid = threadIdx.x;
  const size_t base = (size_t)row * CC;
  float4 v = *(const float4*)(x + base + tid * 4);
  float s = v.x + v.y + v.z + v.w;
  float q = v.x * v.x + v.y * v.y + v.z * v.z + v.w * v.w;
#pragma unroll
  for (int o = 32; o > 0; o >>= 1) {
    s += __shfl_down(s, o, 64);
    q += __shfl_down(q, o, 64);
  }
  __shared__ float red[8];
  __shared__ float stat[2];
  int lane = tid & 63, wid = tid >> 6;
  if (!lane) { red[wid] = s; red[4 + wid] = q; }
  __syncthreads();
  if (!tid) {
    float S = red[0] + red[1] + red[2] + red[3];
    float Q = red[4] + red[5] + red[6] + red[7];
    float mu = S * (1.0f / CC);
    float var = Q * (1.0f / CC) - mu * mu;
    stat[0] = mu;
    stat[1] = rsqrtf(var + 1e-5f);
  }
  __syncthreads();
  float mu = stat[0], rs = stat[1];
  int c = tid * 4;
  float4 gv = *(const float4*)(gw + c);
  float4 bv = *(const float4*)(bw + c);
  ushort4 o;
  o.x = f2bf((v.x - mu) * rs * gv.x + bv.x);
  o.y = f2bf((v.y - mu) * rs * gv.y + bv.y);
  o.z = f2bf((v.z - mu) * rs * gv.z + bv.z);
  o.w = f2bf((v.w - mu) * rs * gv.w + bv.w);
  *(ushort4*)(out + base + c) = o;
}

// ---------------- split-K reduce: d_out = p0 + p1 + bias + resid (f32) --------

__global__ __launch_bounds__(256) void rf2_kernel(const u16* __restrict__ p0,
                                                  const u16* __restrict__ p1,
                                                  const float* __restrict__ b2,
                                                  const float* __restrict__ resid,
                                                  float* __restrict__ out) {
  int c = threadIdx.x * 4;
  size_t i = (size_t)blockIdx.x * CC + c;
  ushort4 a = *(const ushort4*)(p0 + i);
  ushort4 b = *(const ushort4*)(p1 + i);
  float4 r = *(const float4*)(resid + i);
  float4 bb = *(const float4*)(b2 + c);
  float4 o;
  o.x = bf2f(a.x) + bf2f(b.x) + r.x + bb.x;
  o.y = bf2f(a.y) + bf2f(b.y) + r.y + bb.y;
  o.z = bf2f(a.z) + bf2f(b.z) + r.z + bb.z;
  o.w = bf2f(a.w) + bf2f(b.w) + r.w + bb.w;
  *(float4*)(out + i) = o;
}

// ---------------- GEMM 256x256, 8-phase counted-vmcnt (m201 template) ----------
// C[M,N] = A[M,K-slice] * B[N,K-slice]^T ; row stride Kst, loop extent K.
// kslice = sb/kdiv selects K-window [kslice*K, (kslice+1)*K) and partial buffer.
// PERS: grid is halved; each block runs TWO complete, independent pipelines for
//       M-adjacent tiles (2*m2, n) then (2*m2+1, n) — same B-panel.
// EPI: 0 = bf16 store to (kslice ? vt : Cv) | 1 = +resid -> f32
//      2 = +bias, GELU -> bf16 | 3 = +bias +resid -> f32
//      4 = QKV epilogue (Q*0.125*log2e, K, V->VT permuted)

template <int EPI, bool PERS>
__global__ __launch_bounds__(512) void gemm256(const u16* __restrict__ A,
                                               const u16* __restrict__ B,
                                               void* __restrict__ Cv,
                                               const float* __restrict__ bias,
                                               const float* __restrict__ resid,
                                               u16* __restrict__ vt,
                                               int N, int K, int Kst,
                                               int gn, int kdiv) {
  __shared__ u16 lds[8][8192];  // 8 slots x 16KB, each a [256][32] bf16 half-tile
  const int tid = threadIdx.x, lane = tid & 63, wid = tid >> 6;
  const int nwg = gridDim.x;
  const int bid = blockIdx.x;
  const int sb = (nwg & 7) ? bid : ((bid & 7) * (nwg >> 3) + (bid >> 3));
  const int kslice = PERS ? 0 : (sb / kdiv);
  const int rem = PERS ? sb : (sb % kdiv);
  const int tM0 = PERS ? ((rem / gn) * 512) : ((rem / gn) * 256);
  const int tN = (rem % gn) * 256;
  const int wm = wid >> 2, wn = wid & 3;          // 2M x 4N waves
  const int fr = lane & 15, g4 = lane >> 4;       // frag row / k-group
  const int gsw = (g4 ^ ((fr >> 3) << 1)) * 8;    // st_16x32 swizzled k-offset
  const int srow0 = wid * 16 + (lane >> 2);       // staging row (+ i*128)
  const int scol = ((lane & 3) ^ ((lane >> 5) << 1)) * 8;  // inverse-swizzled src col
  const u16* pB = B + (size_t)kslice * K + (size_t)tN * Kst + (size_t)srow0 * Kst + scol;
  const int NKT = K >> 6;
  const int NH = PERS ? 2 : 1;

  for (int half = 0; half < NH; ++half) {
    const int tM = tM0 + half * 256;
    const u16* pA = A + (size_t)kslice * K + (size_t)tM * Kst +
                    (size_t)srow0 * Kst + scol;
    f32x4 acc[8][4] = {};

    auto stage = [&](int idx) {
      int kof = (idx >> 1) << 5;                  // = ts*64 + (half k)*32
      const u16* G = (idx & 1) ? pB : pA;
      u16* dst = &lds[idx & 7][wid * 512];
      gload_lds16(G + kof, dst);
      gload_lds16(G + (size_t)128 * Kst + kof, dst + 4096);
    };

    // prologue: 4 halves, vmcnt(4), 3 halves, vmcnt(6) (3 half-tiles in flight)
#pragma unroll
    for (int j = 0; j < 4; ++j) stage(j);
    asm volatile("s_waitcnt vmcnt(4)" ::: "memory");
#pragma unroll
    for (int j = 4; j < 7; ++j) stage(j);
    asm volatile("s_waitcnt vmcnt(6)" ::: "memory");
    __builtin_amdgcn_s_barrier();

    for (int t2 = 0; t2 < NKT; t2 += 2) {
#pragma unroll
      for (int tt = 0; tt < 2; ++tt) {
        const int t = t2 + tt;
        const int bo = tt << 2;                   // compile-time slot base
#pragma unroll
        for (int ks = 0; ks < 2; ++ks) {
          const u16* Ah = lds[bo | (ks << 1)];
          const u16* Bh = lds[bo | (ks << 1) | 1];
          bf16x8 bfr[4];
#pragma unroll
          for (int ni = 0; ni < 4; ++ni)
            bfr[ni] = *(const bf16x8*)&Bh[(wn * 64 + ni * 16 + fr) * 32 + gsw];
#pragma unroll
          for (int mh = 0; mh < 2; ++mh) {
            bf16x8 af[4];
#pragma unroll
            for (int mi = 0; mi < 4; ++mi)
              af[mi] = *(const bf16x8*)&Ah[(wm * 128 + mh * 64 + mi * 16 + fr) * 32 + gsw];
            __builtin_amdgcn_sched_barrier(0);
            int idx = 4 * t + (ks << 1) + mh + 7; // stage 7 phases ahead
            if (idx < 4 * NKT) stage(idx);
            __builtin_amdgcn_s_barrier();
            asm volatile("s_waitcnt lgkmcnt(0)" ::: "memory");
            __builtin_amdgcn_sched_barrier(0);
            __builtin_amdgcn_s_setprio(1);
#pragma unroll
            for (int mi = 0; mi < 4; ++mi)
#pragma unroll
              for (int ni = 0; ni < 4; ++ni)
                acc[mh * 4 + mi][ni] = __builtin_amdgcn_mfma_f32_16x16x32_bf16(
                    af[mi], bfr[ni], acc[mh * 4 + mi][ni], 0, 0, 0);
            __builtin_amdgcn_s_setprio(0);
            __builtin_amdgcn_sched_barrier(0);
            if (ks == 1 && mh == 1) {             // once per K-tile
              if (t < NKT - 2) asm volatile("s_waitcnt vmcnt(6)" ::: "memory");
              else if (t == NKT - 2) asm volatile("s_waitcnt vmcnt(0)" ::: "memory");
            }
            __builtin_amdgcn_s_barrier();
          }
        }
      }
    }

#pragma unroll
    for (int m = 0; m < 8; ++m) {
#pragma unroll
      for (int ni = 0; ni < 4; ++ni) {
        const int gR0 = tM + wm * 128 + m * 16 + g4 * 4;
        const int gC = tN + wn * 64 + ni * 16 + fr;
        if constexpr (EPI == 4) {
          if (gC < 2048) {
            // Q scaled by D^-0.5 * log2(e) so attn softmax runs in exp2 domain
            float sc = (gC < 1024) ? 0.180336884f : 1.0f;
#pragma unroll
            for (int r = 0; r < 4; ++r)
              ((u16*)Cv)[(size_t)(gR0 + r) * 3072 + gC] = f2bf(acc[m][ni][r] * sc);
          } else {
            int tr = gR0 & 2047, bb = gR0 >> 11;
            int dv = gC - 2048, hh = dv >> 6, dd = dv & 63;
            int k5 = tr & 31;  // multiple of 4
            int pos = ((k5 & 15) >> 2) * 8 + ((k5 >> 4) & 1) * 4;
            ushort4 q4;
            q4.x = f2bf(acc[m][ni][0]);
            q4.y = f2bf(acc[m][ni][1]);
            q4.z = f2bf(acc[m][ni][2]);
            q4.w = f2bf(acc[m][ni][3]);
            *(ushort4*)&vt[((size_t)((bb * 16 + hh) * 64 + dd)) * 2048 + (tr & ~31) + pos] = q4;
          }
        } else if constexpr (EPI == 0) {
          u16* dst = kslice ? vt : (u16*)Cv;
#pragma unroll
          for (int r = 0; r < 4; ++r)
            dst[(size_t)(gR0 + r) * N + gC] = f2bf(acc[m][ni][r]);
        } else if constexpr (EPI == 2) {
#pragma unroll
          for (int r = 0; r < 4; ++r) {
            float v = gelu_tanh(acc[m][ni][r] + bias[gC]);
            ((u16*)Cv)[(size_t)(gR0 + r) * N + gC] = f2bf(v);
          }
        } else {
#pragma unroll
          for (int r = 0; r < 4; ++r) {
            size_t idx = (size_t)(gR0 + r) * N + gC;
            float v = acc[m][ni][r] + resid[idx];
            if constexpr (EPI == 3) v += bias[gC];
            ((float*)Cv)[idx] = v;
          }
        }
      }
    }
  }
}

// ---------------- causal flash attention (swapped-QK^T, in-register P) ----------------
// Q pre-scaled by 0.125*log2e -> softmax in exp2 domain. 1D grid, XCD-chunked.
// Double-buffered K/V with COUNTED vmcnt(4) + raw barriers (no per-tile full
// drain): each wave's stage() = exactly 4 global_load_lds.

__global__ __launch_bounds__(256) void attn_kernel(const u16* __restrict__ qkv,
                                                   const u16* __restrict__ vt,
                                                   u16* __restrict__ out) {
  const int bid = blockIdx.x;
  const int sb = (bid & 7) * 128 + (bid >> 3);   // XCD-chunked remap (1024 blocks)
  const int pair = sb & 15;
  const int bh = sb >> 4;
  const int b = bh >> 4, h = bh & 15;
  const int tid = threadIdx.x, lane = tid & 63, wid = tid >> 6;
  const int ql = lane & 15, g = lane >> 4;
  const int sw = ql & 7;              // read-side swizzle key
  __shared__ u16 Ks[2][4096];         // [64 keys][64 d], XOR-swizzled chunks
  __shared__ u16 Vs[2][4096];         // [64 d][64 keys permuted], XOR-swizzled
  const size_t rowQbase = (size_t)b * TT;
  const u16* kpart = qkv + rowQbase * 3072 + 1024 + h * 64;
  const u16* vpart = vt + ((size_t)(b * 16 + h) * 64) * 2048;
  const int srow = lane >> 3;
  const int sc16 = lane & 7;

  for (int pass = 0; pass < 2; ++pass) {
    const int qt = pass ? (31 - pair) : pair;
    const int qrow0 = qt * 64 + wid * 16;
    const int q_glb = qrow0 + ql;
    const u16* qp = qkv + (rowQbase + q_glb) * 3072 + h * 64 + g * 8;
    bf16x8 qf0 = *(const bf16x8*)qp;
    bf16x8 qf1 = *(const bf16x8*)(qp + 32);
    f32x4 o[4] = {};
    float m_run = -1e30f, l_run = 0.f;
    const int nt = qt + 1;

    auto stage = [&](int bufi, int t) {
      int kv0 = t * 64;
#pragma unroll
      for (int i = 0; i < 2; ++i) {
        int seg = wid * 2 + i;
        int rloc = seg * 8 + srow;
        int cs = (sc16 ^ (rloc & 7)) * 8;
        gload_lds16(kpart + (size_t)(kv0 + rloc) * 3072 + cs, &Ks[bufi][seg * 512]);
        gload_lds16(vpart + (size_t)rloc * 2048 + kv0 + cs, &Vs[bufi][seg * 512]);
      }
    };

    stage(0, 0);
    __syncthreads();
    int buf = 0;
    for (int t = 0; t < nt; ++t) {
      // prefetch next tile, then wait only for CURRENT buffer's 4 loads
      if (t + 1 < nt) {
        stage(buf ^ 1, t + 1);
        asm volatile("s_waitcnt vmcnt(4)" ::: "memory");
      } else {
        asm volatile("s_waitcnt vmcnt(0)" ::: "memory");
      }
      __builtin_amdgcn_s_barrier();       // all waves: buf resident in LDS
      __builtin_amdgcn_sched_barrier(0);
      const u16* Kb = Ks[buf];
      const u16* Vb = Vs[buf];
      const int kv0 = t * 64;
      float p[16];
      __builtin_amdgcn_s_setprio(1);
#pragma unroll
      for (int kt = 0; kt < 4; ++kt) {
        int row = kt * 16 + ql;
        bf16x8 k0 = *(const bf16x8*)&Kb[row * 64 + ((g ^ sw) * 8)];
        bf16x8 k1 = *(const bf16x8*)&Kb[row * 64 + (((4 + g) ^ sw) * 8)];
        f32x4 s = {0.f, 0.f, 0.f, 0.f};
        s = __builtin_amdgcn_mfma_f32_16x16x32_bf16(k0, qf0, s, 0, 0, 0);
        s = __builtin_amdgcn_mfma_f32_16x16x32_bf16(k1, qf1, s, 0, 0, 0);
        if (t == qt) {
#pragma unroll
          for (int r = 0; r < 4; ++r) {
            int k_glb = kv0 + kt * 16 + 4 * g + r;
            p[kt * 4 + r] = (k_glb <= q_glb) ? s[r] : -1e30f;
          }
        } else {
#pragma unroll
          for (int r = 0; r < 4; ++r) p[kt * 4 + r] = s[r];
        }
      }
      __builtin_amdgcn_s_setprio(0);
      // ---- online softmax (exp2 domain), tree reductions ----
      float t8[8];
#pragma unroll
      for (int i = 0; i < 8; ++i) t8[i] = fmaxf(p[i], p[i + 8]);
#pragma unroll
      for (int i = 0; i < 4; ++i) t8[i] = fmaxf(t8[i], t8[i + 4]);
      float mloc = fmaxf(fmaxf(t8[0], t8[1]), fmaxf(t8[2], t8[3]));
      mloc = fmaxf(mloc, __shfl_xor(mloc, 16));
      mloc = fmaxf(mloc, __shfl_xor(mloc, 32));
      if (!__all(mloc <= m_run + 8.f)) {         // defer-max: P bounded by 2^8
        float mnew = fmaxf(m_run, mloc);
        float alpha = fexp2(m_run - mnew);
        m_run = mnew;
        l_run *= alpha;
        float aO[4];
#pragma unroll
        for (int r = 0; r < 4; ++r) aO[r] = __shfl(alpha, 4 * g + r);
#pragma unroll
        for (int d0 = 0; d0 < 4; ++d0)
#pragma unroll
          for (int r = 0; r < 4; ++r) o[d0][r] *= aO[r];
      }
      float e[16];
#pragma unroll
      for (int i = 0; i < 16; ++i) e[i] = fexp2(p[i] - m_run);
      float s8[8];
#pragma unroll
      for (int i = 0; i < 8; ++i) s8[i] = e[i] + e[i + 8];
#pragma unroll
      for (int i = 0; i < 4; ++i) s8[i] += s8[i + 4];
      float lloc = (s8[0] + s8[1]) + (s8[2] + s8[3]);
      lloc += __shfl_xor(lloc, 16);
      lloc += __shfl_xor(lloc, 32);
      l_run += lloc;
      // pack P -> bf16 via v_cvt_pk_bf16_f32 (RNE), 8 insts for 16 values
      int4 w0, w1;
      asm("v_cvt_pk_bf16_f32 %0, %1, %2" : "=v"(w0.x) : "v"(e[0]), "v"(e[1]));
      asm("v_cvt_pk_bf16_f32 %0, %1, %2" : "=v"(w0.y) : "v"(e[2]), "v"(e[3]));
      asm("v_cvt_pk_bf16_f32 %0, %1, %2" : "=v"(w0.z) : "v"(e[4]), "v"(e[5]));
      asm("v_cvt_pk_bf16_f32 %0, %1, %2" : "=v"(w0.w) : "v"(e[6]), "v"(e[7]));
      asm("v_cvt_pk_bf16_f32 %0, %1, %2" : "=v"(w1.x) : "v"(e[8]), "v"(e[9]));
      asm("v_cvt_pk_bf16_f32 %0, %1, %2" : "=v"(w1.y) : "v"(e[10]), "v"(e[11]));
      asm("v_cvt_pk_bf16_f32 %0, %1, %2" : "=v"(w1.z) : "v"(e[12]), "v"(e[13]));
      asm("v_cvt_pk_bf16_f32 %0, %1, %2" : "=v"(w1.w) : "v"(e[14]), "v"(e[15]));
      bf16x8 pa0 = __builtin_bit_cast(bf16x8, w0);
      bf16x8 pa1 = __builtin_bit_cast(bf16x8, w1);
      __builtin_amdgcn_s_setprio(1);
#pragma unroll
      for (int d0 = 0; d0 < 4; ++d0) {
        int row = d0 * 16 + ql;
        bf16x8 v0 = *(const bf16x8*)&Vb[row * 64 + ((g ^ sw) * 8)];
        bf16x8 v1 = *(const bf16x8*)&Vb[row * 64 + (((4 + g) ^ sw) * 8)];
        o[d0] = __builtin_amdgcn_mfma_f32_16x16x32_bf16(pa0, v0, o[d0], 0, 0, 0);
        o[d0] = __builtin_amdgcn_mfma_f32_16x16x32_bf16(pa1, v1, o[d0], 0, 0, 0);
      }
      __builtin_amdgcn_s_setprio(0);
      __builtin_amdgcn_s_barrier();       // reads of buf done before overwrite
      buf ^= 1;
    }
    float linv = 1.0f / l_run;
    float lO[4];
#pragma unroll
    for (int r = 0; r < 4; ++r) lO[r] = __shfl(linv, 4 * g + r);
#pragma unroll
    for (int d0 = 0; d0 < 4; ++d0) {
#pragma unroll
      for (int r = 0; r < 4; ++r) {
        size_t idx = (rowQbase + qrow0 + 4 * g + r) * CC + h * 64 + d0 * 16 + ql;
        out[idx] = f2bf(o[d0][r] * lO[r]);
      }
    }
  }
}

// ---------------- launch ----------------

extern "C" void kernel_launch(void* const* d_in, const int* in_sizes, int n_in,
                              void* d_out, int out_size, void* d_ws, size_t ws_size,
                              hipStream_t stream) {
  const float* x   = (const float*)d_in[0];
  const float* Wq  = (const float*)d_in[1];
  const float* Wk  = (const float*)d_in[2];
  const float* Wv  = (const float*)d_in[3];
  const float* Wo  = (const float*)d_in[4];
  const float* W1  = (const float*)d_in[5];
  const float* b1  = (const float*)d_in[6];
  const float* W2  = (const float*)d_in[7];
  const float* b2  = (const float*)d_in[8];
  const float* g1  = (const float*)d_in[9];
  const float* be1 = (const float*)d_in[10];
  const float* g2  = (const float*)d_in[11];
  const float* be2 = (const float*)d_in[12];

  char* ws = (char*)d_ws;
  size_t off = 0;
  u16* Wqkv = (u16*)(ws + off); off += (size_t)3072 * 1024 * 2;
  u16* Wob  = (u16*)(ws + off); off += (size_t)1024 * 1024 * 2;
  u16* W1T  = (u16*)(ws + off); off += (size_t)4096 * 1024 * 2;
  u16* W2T  = (u16*)(ws + off); off += (size_t)1024 * 4096 * 2;
  u16* Hb   = (u16*)(ws + off); off += (size_t)BT * 1024 * 2;
  u16* QKV  = (u16*)(ws + off); off += (size_t)BT * 3072 * 2;
  u16* AttO = (u16*)(ws + off); off += (size_t)BT * 1024 * 2;
  float* X2 = (float*)(ws + off); off += (size_t)BT * 1024 * 4;
  u16* FF1 = QKV;        // [8192][4096] overlays QKV+AttO exactly (both dead by then)
  u16* VT  = (u16*)X2;   // 16.8MB <= 32MB; dead before X2 is written (Wo GEMM)
  if (ws_size < off) return;
  const int KBIG = 1 << 20;  // kdiv for non-split calls

  // fused prep: Wq/Wk/Wv/Wo cvt + W1/W2 transpose + LN1, one launch
  prep_kernel<<<20480, 256, 0, stream>>>(Wq, Wk, Wv, Wo, W1, W2, x, g1, be1,
                                         Wqkv, W1T, W2T, Hb);
  gemm256<4, false><<<32 * 12, 512, 0, stream>>>(Hb, Wqkv, QKV, nullptr, nullptr, VT,
                                                 3072, 1024, 1024, 12, KBIG);
  attn_kernel<<<1024, 256, 0, stream>>>(QKV, VT, AttO);
  gemm256<1, false><<<32 * 4, 512, 0, stream>>>(AttO, Wob, X2, nullptr, x, nullptr,
                                                1024, 1024, 1024, 4, KBIG);
  ln_kernel<<<BT, 256, 0, stream>>>(X2, g2, be2, Hb);
  // FF1: persistent M-paired blocks (2 full pipelines, shared B-panel), grid 256
  gemm256<2, true><<<256, 512, 0, stream>>>(Hb, W1T, FF1, b1, nullptr, nullptr,
                                            4096, 1024, 1024, 16, KBIG);
  // FF2 split-K x2: full-chip grid 256; bf16 partials into dead Hb/AttO
  gemm256<0, false><<<32 * 8, 512, 0, stream>>>(FF1, W2T, Hb, nullptr, nullptr, AttO,
                                                1024, 2048, 4096, 4, 128);
  rf2_kernel<<<BT, 256, 0, stream>>>(Hb, AttO, b2, X2, (float*)d_out);
}

// Round 16
// 370.558 us; speedup vs baseline: 1.0239x; 1.0056x over previous
//
#include <hip/hip_runtime.h>
#include <cmath>

typedef unsigned short u16;
typedef __attribute__((ext_vector_type(8))) short bf16x8;
typedef __attribute__((ext_vector_type(4))) float f32x4;

#define TT 2048
#define CC 1024
#define BT 8192   // B*T

__device__ __forceinline__ float fexp2(float x) {
  return __builtin_amdgcn_exp2f(x);   // v_exp_f32 (HW exp2)
}

__device__ __forceinline__ u16 f2bf(float f) {
  unsigned u = __builtin_bit_cast(unsigned, f);
  u += 0x7fffu + ((u >> 16) & 1u);
  return (u16)(u >> 16);
}

__device__ __forceinline__ float bf2f(u16 u) {
  return __builtin_bit_cast(float, (unsigned)u << 16);
}

__device__ __forceinline__ float gelu_tanh(float v) {
  // 0.5v(1+tanh(0.79788456(v+0.044715v^3))) = v*sigmoid(1.59576912v+0.07135482v^3)
  float u2 = v * (1.595769122f + 0.071354816f * v * v);
  return v / (1.f + __expf(-u2));
}

__device__ __forceinline__ void gload_lds16(const void* g, void* l) {
  __builtin_amdgcn_global_load_lds(
      (const __attribute__((address_space(1))) void*)g,
      (__attribute__((address_space(3))) void*)l, 16, 0, 0);
}

// ---------------- fused prep: weight cvt + 2 transposes + LN1 (one launch) ----
// blocks [0,4096):    Wq/Wk/Wv/Wo f32->bf16 into Wqkv (contiguous segments)
// blocks [4096,8192): W1 [1024][4096] -> W1T [4096][1024] bf16
// blocks [8192,12288):W2 [4096][1024] -> W2T [1024][4096] bf16
// blocks [12288,20480): LN1 row -> Hb bf16

__global__ __launch_bounds__(256) void prep_kernel(
    const float* __restrict__ Wq, const float* __restrict__ Wk,
    const float* __restrict__ Wv, const float* __restrict__ Wo,
    const float* __restrict__ W1, const float* __restrict__ W2,
    const float* __restrict__ x,  const float* __restrict__ g1,
    const float* __restrict__ be1,
    u16* __restrict__ Wqkv, u16* __restrict__ W1T, u16* __restrict__ W2T,
    u16* __restrict__ Hb) {
  const int blk = blockIdx.x;
  const int tid = threadIdx.x;
  if (blk < 4096) {                      // ---- cvt4 ----
    int seg = blk >> 10;
    const float* s = (seg == 0) ? Wq : (seg == 1) ? Wk : (seg == 2) ? Wv : Wo;
    int i = ((blk & 1023) * 256 + tid) * 4;
    float4 v = *(const float4*)(s + i);
    ushort4 o;
    o.x = f2bf(v.x); o.y = f2bf(v.y); o.z = f2bf(v.z); o.w = f2bf(v.w);
    *(ushort4*)(Wqkv + (seg << 20) + i) = o;
  } else if (blk < 12288) {              // ---- transpose_cvt ----
    __shared__ float tile[32][33];
    const bool w1 = blk < 8192;
    const int idx = blk - (w1 ? 4096 : 8192);
    const float* src = w1 ? W1 : W2;
    u16* dst = w1 ? W1T : W2T;
    const int R = w1 ? 1024 : 4096, C = w1 ? 4096 : 1024;
    const int c0 = (w1 ? (idx & 127) : (idx & 31)) * 32;
    const int r0 = (w1 ? (idx >> 7) : (idx >> 5)) * 32;
    const int tx = tid & 31, ty = tid >> 5;
#pragma unroll
    for (int j = 0; j < 4; ++j)
      tile[ty + j * 8][tx] = src[(size_t)(r0 + ty + j * 8) * C + c0 + tx];
    __syncthreads();
#pragma unroll
    for (int j = 0; j < 4; ++j)
      dst[(size_t)(c0 + ty + j * 8) * R + r0 + tx] = f2bf(tile[tx][ty + j * 8]);
  } else {                               // ---- LN1 ----
    __shared__ float red[8];
    __shared__ float stat[2];
    const int row = blk - 12288;
    const size_t base = (size_t)row * CC;
    float4 v = *(const float4*)(x + base + tid * 4);
    float s = v.x + v.y + v.z + v.w;
    float q = v.x * v.x + v.y * v.y + v.z * v.z + v.w * v.w;
#pragma unroll
    for (int o = 32; o > 0; o >>= 1) {
      s += __shfl_down(s, o, 64);
      q += __shfl_down(q, o, 64);
    }
    int lane = tid & 63, wid = tid >> 6;
    if (!lane) { red[wid] = s; red[4 + wid] = q; }
    __syncthreads();
    if (!tid) {
      float S = red[0] + red[1] + red[2] + red[3];
      float Q = red[4] + red[5] + red[6] + red[7];
      float mu = S * (1.0f / CC);
      float var = Q * (1.0f / CC) - mu * mu;
      stat[0] = mu;
      stat[1] = rsqrtf(var + 1e-5f);
    }
    __syncthreads();
    float mu = stat[0], rs = stat[1];
    int c = tid * 4;
    float4 gv = *(const float4*)(g1 + c);
    float4 bv = *(const float4*)(be1 + c);
    ushort4 o;
    o.x = f2bf((v.x - mu) * rs * gv.x + bv.x);
    o.y = f2bf((v.y - mu) * rs * gv.y + bv.y);
    o.z = f2bf((v.z - mu) * rs * gv.z + bv.z);
    o.w = f2bf((v.w - mu) * rs * gv.w + bv.w);
    *(ushort4*)(Hb + base + c) = o;
  }
}

// ---------------- layernorm (f32 in -> bf16 out) ----------------

__global__ __launch_bounds__(256) void ln_kernel(const float* __restrict__ x,
                                                 const float* __restrict__ gw,
                                                 const float* __restrict__ bw,
                                                 u16* __restrict__ out) {
  int row = blockIdx.x;
  int tid = threadIdx.x;
  const size_t base = (size_t)row * CC;
  float4 v = *(const float4*)(x + base + tid * 4);
  float s = v.x + v.y + v.z + v.w;
  float q = v.x * v.x + v.y * v.y + v.z * v.z + v.w * v.w;
#pragma unroll
  for (int o = 32; o > 0; o >>= 1) {
    s += __shfl_down(s, o, 64);
    q += __shfl_down(q, o, 64);
  }
  __shared__ float red[8];
  __shared__ float stat[2];
  int lane = tid & 63, wid = tid >> 6;
  if (!lane) { red[wid] = s; red[4 + wid] = q; }
  __syncthreads();
  if (!tid) {
    float S = red[0] + red[1] + red[2] + red[3];
    float Q = red[4] + red[5] + red[6] + red[7];
    float mu = S * (1.0f / CC);
    float var = Q * (1.0f / CC) - mu * mu;
    stat[0] = mu;
    stat[1] = rsqrtf(var + 1e-5f);
  }
  __syncthreads();
  float mu = stat[0], rs = stat[1];
  int c = tid * 4;
  float4 gv = *(const float4*)(gw + c);
  float4 bv = *(const float4*)(bw + c);
  ushort4 o;
  o.x = f2bf((v.x - mu) * rs * gv.x + bv.x);
  o.y = f2bf((v.y - mu) * rs * gv.y + bv.y);
  o.z = f2bf((v.z - mu) * rs * gv.z + bv.z);
  o.w = f2bf((v.w - mu) * rs * gv.w + bv.w);
  *(ushort4*)(out + base + c) = o;
}

// ---------------- split-K reduce: d_out = p0 + p1 + bias + resid (f32) --------

__global__ __launch_bounds__(256) void rf2_kernel(const u16* __restrict__ p0,
                                                  const u16* __restrict__ p1,
                                                  const float* __restrict__ b2,
                                                  const float* __restrict__ resid,
                                                  float* __restrict__ out) {
  int c = threadIdx.x * 4;
  size_t i = (size_t)blockIdx.x * CC + c;
  ushort4 a = *(const ushort4*)(p0 + i);
  ushort4 b = *(const ushort4*)(p1 + i);
  float4 r = *(const float4*)(resid + i);
  float4 bb = *(const float4*)(b2 + c);
  float4 o;
  o.x = bf2f(a.x) + bf2f(b.x) + r.x + bb.x;
  o.y = bf2f(a.y) + bf2f(b.y) + r.y + bb.y;
  o.z = bf2f(a.z) + bf2f(b.z) + r.z + bb.z;
  o.w = bf2f(a.w) + bf2f(b.w) + r.w + bb.w;
  *(float4*)(out + i) = o;
}

// ---------------- GEMM 256x256, 8-phase counted-vmcnt (m201 template) ----------
// C[M,N] = A[M,K-slice] * B[N,K-slice]^T ; row stride Kst, loop extent K.
// kslice = sb/kdiv selects K-window [kslice*K, (kslice+1)*K) and partial buffer.
// PERS: grid is halved; each block runs TWO complete, independent pipelines for
//       M-adjacent tiles (2*m2, n) then (2*m2+1, n) — same B-panel.
// EPI: 0 = bf16 store to (kslice ? vt : Cv) | 1 = +resid -> f32
//      2 = +bias, GELU -> bf16 | 3 = +bias +resid -> f32
//      4 = QKV epilogue (Q*0.125*log2e, K, V->VT permuted)

template <int EPI, bool PERS>
__global__ __launch_bounds__(512) void gemm256(const u16* __restrict__ A,
                                               const u16* __restrict__ B,
                                               void* __restrict__ Cv,
                                               const float* __restrict__ bias,
                                               const float* __restrict__ resid,
                                               u16* __restrict__ vt,
                                               int N, int K, int Kst,
                                               int gn, int kdiv) {
  __shared__ u16 lds[8][8192];  // 8 slots x 16KB, each a [256][32] bf16 half-tile
  const int tid = threadIdx.x, lane = tid & 63, wid = tid >> 6;
  const int nwg = gridDim.x;
  const int bid = blockIdx.x;
  const int sb = (nwg & 7) ? bid : ((bid & 7) * (nwg >> 3) + (bid >> 3));
  const int kslice = PERS ? 0 : (sb / kdiv);
  const int rem = PERS ? sb : (sb % kdiv);
  const int tM0 = PERS ? ((rem / gn) * 512) : ((rem / gn) * 256);
  const int tN = (rem % gn) * 256;
  const int wm = wid >> 2, wn = wid & 3;          // 2M x 4N waves
  const int fr = lane & 15, g4 = lane >> 4;       // frag row / k-group
  const int gsw = (g4 ^ ((fr >> 3) << 1)) * 8;    // st_16x32 swizzled k-offset
  const int srow0 = wid * 16 + (lane >> 2);       // staging row (+ i*128)
  const int scol = ((lane & 3) ^ ((lane >> 5) << 1)) * 8;  // inverse-swizzled src col
  const u16* pB = B + (size_t)kslice * K + (size_t)tN * Kst + (size_t)srow0 * Kst + scol;
  const int NKT = K >> 6;
  const int NH = PERS ? 2 : 1;

  for (int half = 0; half < NH; ++half) {
    const int tM = tM0 + half * 256;
    const u16* pA = A + (size_t)kslice * K + (size_t)tM * Kst +
                    (size_t)srow0 * Kst + scol;
    f32x4 acc[8][4] = {};

    auto stage = [&](int idx) {
      int kof = (idx >> 1) << 5;                  // = ts*64 + (half k)*32
      const u16* G = (idx & 1) ? pB : pA;
      u16* dst = &lds[idx & 7][wid * 512];
      gload_lds16(G + kof, dst);
      gload_lds16(G + (size_t)128 * Kst + kof, dst + 4096);
    };

    // prologue: 4 halves, vmcnt(4), 3 halves, vmcnt(6) (3 half-tiles in flight)
#pragma unroll
    for (int j = 0; j < 4; ++j) stage(j);
    asm volatile("s_waitcnt vmcnt(4)" ::: "memory");
#pragma unroll
    for (int j = 4; j < 7; ++j) stage(j);
    asm volatile("s_waitcnt vmcnt(6)" ::: "memory");
    __builtin_amdgcn_s_barrier();

    for (int t2 = 0; t2 < NKT; t2 += 2) {
#pragma unroll
      for (int tt = 0; tt < 2; ++tt) {
        const int t = t2 + tt;
        const int bo = tt << 2;                   // compile-time slot base
#pragma unroll
        for (int ks = 0; ks < 2; ++ks) {
          const u16* Ah = lds[bo | (ks << 1)];
          const u16* Bh = lds[bo | (ks << 1) | 1];
          bf16x8 bfr[4];
#pragma unroll
          for (int ni = 0; ni < 4; ++ni)
            bfr[ni] = *(const bf16x8*)&Bh[(wn * 64 + ni * 16 + fr) * 32 + gsw];
#pragma unroll
          for (int mh = 0; mh < 2; ++mh) {
            bf16x8 af[4];
#pragma unroll
            for (int mi = 0; mi < 4; ++mi)
              af[mi] = *(const bf16x8*)&Ah[(wm * 128 + mh * 64 + mi * 16 + fr) * 32 + gsw];
            __builtin_amdgcn_sched_barrier(0);
            int idx = 4 * t + (ks << 1) + mh + 7; // stage 7 phases ahead
            if (idx < 4 * NKT) stage(idx);
            __builtin_amdgcn_s_barrier();
            asm volatile("s_waitcnt lgkmcnt(0)" ::: "memory");
            __builtin_amdgcn_sched_barrier(0);
            __builtin_amdgcn_s_setprio(1);
#pragma unroll
            for (int mi = 0; mi < 4; ++mi)
#pragma unroll
              for (int ni = 0; ni < 4; ++ni)
                acc[mh * 4 + mi][ni] = __builtin_amdgcn_mfma_f32_16x16x32_bf16(
                    af[mi], bfr[ni], acc[mh * 4 + mi][ni], 0, 0, 0);
            __builtin_amdgcn_s_setprio(0);
            __builtin_amdgcn_sched_barrier(0);
            if (ks == 1 && mh == 1) {             // once per K-tile
              if (t < NKT - 2) asm volatile("s_waitcnt vmcnt(6)" ::: "memory");
              else if (t == NKT - 2) asm volatile("s_waitcnt vmcnt(0)" ::: "memory");
            }
            __builtin_amdgcn_s_barrier();
          }
        }
      }
    }

#pragma unroll
    for (int m = 0; m < 8; ++m) {
#pragma unroll
      for (int ni = 0; ni < 4; ++ni) {
        const int gR0 = tM + wm * 128 + m * 16 + g4 * 4;
        const int gC = tN + wn * 64 + ni * 16 + fr;
        if constexpr (EPI == 4) {
          if (gC < 2048) {
            // Q scaled by D^-0.5 * log2(e) so attn softmax runs in exp2 domain
            float sc = (gC < 1024) ? 0.180336884f : 1.0f;
#pragma unroll
            for (int r = 0; r < 4; ++r)
              ((u16*)Cv)[(size_t)(gR0 + r) * 3072 + gC] = f2bf(acc[m][ni][r] * sc);
          } else {
            int tr = gR0 & 2047, bb = gR0 >> 11;
            int dv = gC - 2048, hh = dv >> 6, dd = dv & 63;
            int k5 = tr & 31;  // multiple of 4
            int pos = ((k5 & 15) >> 2) * 8 + ((k5 >> 4) & 1) * 4;
            ushort4 q4;
            q4.x = f2bf(acc[m][ni][0]);
            q4.y = f2bf(acc[m][ni][1]);
            q4.z = f2bf(acc[m][ni][2]);
            q4.w = f2bf(acc[m][ni][3]);
            *(ushort4*)&vt[((size_t)((bb * 16 + hh) * 64 + dd)) * 2048 + (tr & ~31) + pos] = q4;
          }
        } else if constexpr (EPI == 0) {
          u16* dst = kslice ? vt : (u16*)Cv;
#pragma unroll
          for (int r = 0; r < 4; ++r)
            dst[(size_t)(gR0 + r) * N + gC] = f2bf(acc[m][ni][r]);
        } else if constexpr (EPI == 2) {
#pragma unroll
          for (int r = 0; r < 4; ++r) {
            float v = gelu_tanh(acc[m][ni][r] + bias[gC]);
            ((u16*)Cv)[(size_t)(gR0 + r) * N + gC] = f2bf(v);
          }
        } else {
#pragma unroll
          for (int r = 0; r < 4; ++r) {
            size_t idx = (size_t)(gR0 + r) * N + gC;
            float v = acc[m][ni][r] + resid[idx];
            if constexpr (EPI == 3) v += bias[gC];
            ((float*)Cv)[idx] = v;
          }
        }
      }
    }
  }
}

// ---------------- causal flash attention (swapped-QK^T, in-register P) ----------------
// Q pre-scaled by 0.125*log2e -> softmax in exp2 domain. 1D grid, XCD-chunked.
// Both q-tile passes share ONE continuous staging pipeline: pass-0's last tile
// prefetches pass-1's tile 0 (same K/V data, L2-hot) instead of draining; the
// second prologue disappears. Counted vmcnt(4) per tile; vmcnt(0) only at end.

__global__ __launch_bounds__(256) void attn_kernel(const u16* __restrict__ qkv,
                                                   const u16* __restrict__ vt,
                                                   u16* __restrict__ out) {
  const int bid = blockIdx.x;
  const int sb = (bid & 7) * 128 + (bid >> 3);   // XCD-chunked remap (1024 blocks)
  const int pair = sb & 15;
  const int bh = sb >> 4;
  const int b = bh >> 4, h = bh & 15;
  const int tid = threadIdx.x, lane = tid & 63, wid = tid >> 6;
  const int ql = lane & 15, g = lane >> 4;
  const int sw = ql & 7;              // read-side swizzle key
  __shared__ u16 Ks[2][4096];         // [64 keys][64 d], XOR-swizzled chunks
  __shared__ u16 Vs[2][4096];         // [64 d][64 keys permuted], XOR-swizzled
  const size_t rowQbase = (size_t)b * TT;
  const u16* kpart = qkv + rowQbase * 3072 + 1024 + h * 64;
  const u16* vpart = vt + ((size_t)(b * 16 + h) * 64) * 2048;
  const int srow = lane >> 3;
  const int sc16 = lane & 7;

  auto stage = [&](int bufi, int t) {
    int kv0 = t * 64;
#pragma unroll
    for (int i = 0; i < 2; ++i) {
      int seg = wid * 2 + i;
      int rloc = seg * 8 + srow;
      int cs = (sc16 ^ (rloc & 7)) * 8;
      gload_lds16(kpart + (size_t)(kv0 + rloc) * 3072 + cs, &Ks[bufi][seg * 512]);
      gload_lds16(vpart + (size_t)rloc * 2048 + kv0 + cs, &Vs[bufi][seg * 512]);
    }
  };

  stage(0, 0);
  __syncthreads();
  int buf = 0;

  for (int pass = 0; pass < 2; ++pass) {
    const int qt = pass ? (31 - pair) : pair;
    const int qrow0 = qt * 64 + wid * 16;
    const int q_glb = qrow0 + ql;
    const u16* qp = qkv + (rowQbase + q_glb) * 3072 + h * 64 + g * 8;
    bf16x8 qf0 = *(const bf16x8*)qp;
    bf16x8 qf1 = *(const bf16x8*)(qp + 32);
    f32x4 o[4] = {};
    float m_run = -1e30f, l_run = 0.f;
    const int nt = qt + 1;

    for (int t = 0; t < nt; ++t) {
      // prefetch next tile in the CONTINUOUS stream (pass-0 tail prefetches
      // pass-1's tile 0); wait only for CURRENT buffer's 4 loads
      const bool last_overall = (pass == 1) && (t + 1 == nt);
      if (!last_overall) {
        stage(buf ^ 1, (t + 1 < nt) ? t + 1 : 0);
        asm volatile("s_waitcnt vmcnt(4)" ::: "memory");
      } else {
        asm volatile("s_waitcnt vmcnt(0)" ::: "memory");
      }
      __builtin_amdgcn_s_barrier();       // all waves: buf resident in LDS
      __builtin_amdgcn_sched_barrier(0);
      const u16* Kb = Ks[buf];
      const u16* Vb = Vs[buf];
      const int kv0 = t * 64;
      float p[16];
      __builtin_amdgcn_s_setprio(1);
#pragma unroll
      for (int kt = 0; kt < 4; ++kt) {
        int row = kt * 16 + ql;
        bf16x8 k0 = *(const bf16x8*)&Kb[row * 64 + ((g ^ sw) * 8)];
        bf16x8 k1 = *(const bf16x8*)&Kb[row * 64 + (((4 + g) ^ sw) * 8)];
        f32x4 s = {0.f, 0.f, 0.f, 0.f};
        s = __builtin_amdgcn_mfma_f32_16x16x32_bf16(k0, qf0, s, 0, 0, 0);
        s = __builtin_amdgcn_mfma_f32_16x16x32_bf16(k1, qf1, s, 0, 0, 0);
        if (t == qt) {
#pragma unroll
          for (int r = 0; r < 4; ++r) {
            int k_glb = kv0 + kt * 16 + 4 * g + r;
            p[kt * 4 + r] = (k_glb <= q_glb) ? s[r] : -1e30f;
          }
        } else {
#pragma unroll
          for (int r = 0; r < 4; ++r) p[kt * 4 + r] = s[r];
        }
      }
      __builtin_amdgcn_s_setprio(0);
      // ---- online softmax (exp2 domain), tree reductions ----
      float t8[8];
#pragma unroll
      for (int i = 0; i < 8; ++i) t8[i] = fmaxf(p[i], p[i + 8]);
#pragma unroll
      for (int i = 0; i < 4; ++i) t8[i] = fmaxf(t8[i], t8[i + 4]);
      float mloc = fmaxf(fmaxf(t8[0], t8[1]), fmaxf(t8[2], t8[3]));
      mloc = fmaxf(mloc, __shfl_xor(mloc, 16));
      mloc = fmaxf(mloc, __shfl_xor(mloc, 32));
      if (!__all(mloc <= m_run + 8.f)) {         // defer-max: P bounded by 2^8
        float mnew = fmaxf(m_run, mloc);
        float alpha = fexp2(m_run - mnew);
        m_run = mnew;
        l_run *= alpha;
        float aO[4];
#pragma unroll
        for (int r = 0; r < 4; ++r) aO[r] = __shfl(alpha, 4 * g + r);
#pragma unroll
        for (int d0 = 0; d0 < 4; ++d0)
#pragma unroll
          for (int r = 0; r < 4; ++r) o[d0][r] *= aO[r];
      }
      float e[16];
#pragma unroll
      for (int i = 0; i < 16; ++i) e[i] = fexp2(p[i] - m_run);
      float s8[8];
#pragma unroll
      for (int i = 0; i < 8; ++i) s8[i] = e[i] + e[i + 8];
#pragma unroll
      for (int i = 0; i < 4; ++i) s8[i] += s8[i + 4];
      float lloc = (s8[0] + s8[1]) + (s8[2] + s8[3]);
      lloc += __shfl_xor(lloc, 16);
      lloc += __shfl_xor(lloc, 32);
      l_run += lloc;
      // pack P -> bf16 via v_cvt_pk_bf16_f32 (RNE), 8 insts for 16 values
      int4 w0, w1;
      asm("v_cvt_pk_bf16_f32 %0, %1, %2" : "=v"(w0.x) : "v"(e[0]), "v"(e[1]));
      asm("v_cvt_pk_bf16_f32 %0, %1, %2" : "=v"(w0.y) : "v"(e[2]), "v"(e[3]));
      asm("v_cvt_pk_bf16_f32 %0, %1, %2" : "=v"(w0.z) : "v"(e[4]), "v"(e[5]));
      asm("v_cvt_pk_bf16_f32 %0, %1, %2" : "=v"(w0.w) : "v"(e[6]), "v"(e[7]));
      asm("v_cvt_pk_bf16_f32 %0, %1, %2" : "=v"(w1.x) : "v"(e[8]), "v"(e[9]));
      asm("v_cvt_pk_bf16_f32 %0, %1, %2" : "=v"(w1.y) : "v"(e[10]), "v"(e[11]));
      asm("v_cvt_pk_bf16_f32 %0, %1, %2" : "=v"(w1.z) : "v"(e[12]), "v"(e[13]));
      asm("v_cvt_pk_bf16_f32 %0, %1, %2" : "=v"(w1.w) : "v"(e[14]), "v"(e[15]));
      bf16x8 pa0 = __builtin_bit_cast(bf16x8, w0);
      bf16x8 pa1 = __builtin_bit_cast(bf16x8, w1);
      __builtin_amdgcn_s_setprio(1);
#pragma unroll
      for (int d0 = 0; d0 < 4; ++d0) {
        int row = d0 * 16 + ql;
        bf16x8 v0 = *(const bf16x8*)&Vb[row * 64 + ((g ^ sw) * 8)];
        bf16x8 v1 = *(const bf16x8*)&Vb[row * 64 + (((4 + g) ^ sw) * 8)];
        o[d0] = __builtin_amdgcn_mfma_f32_16x16x32_bf16(pa0, v0, o[d0], 0, 0, 0);
        o[d0] = __builtin_amdgcn_mfma_f32_16x16x32_bf16(pa1, v1, o[d0], 0, 0, 0);
      }
      __builtin_amdgcn_s_setprio(0);
      __builtin_amdgcn_s_barrier();       // reads of buf done before overwrite
      buf ^= 1;
    }
    float linv = 1.0f / l_run;
    float lO[4];
#pragma unroll
    for (int r = 0; r < 4; ++r) lO[r] = __shfl(linv, 4 * g + r);
#pragma unroll
    for (int d0 = 0; d0 < 4; ++d0) {
#pragma unroll
      for (int r = 0; r < 4; ++r) {
        size_t idx = (rowQbase + qrow0 + 4 * g + r) * CC + h * 64 + d0 * 16 + ql;
        out[idx] = f2bf(o[d0][r] * lO[r]);
      }
    }
  }
}

// ---------------- launch ----------------

extern "C" void kernel_launch(void* const* d_in, const int* in_sizes, int n_in,
                              void* d_out, int out_size, void* d_ws, size_t ws_size,
                              hipStream_t stream) {
  const float* x   = (const float*)d_in[0];
  const float* Wq  = (const float*)d_in[1];
  const float* Wk  = (const float*)d_in[2];
  const float* Wv  = (const float*)d_in[3];
  const float* Wo  = (const float*)d_in[4];
  const float* W1  = (const float*)d_in[5];
  const float* b1  = (const float*)d_in[6];
  const float* W2  = (const float*)d_in[7];
  const float* b2  = (const float*)d_in[8];
  const float* g1  = (const float*)d_in[9];
  const float* be1 = (const float*)d_in[10];
  const float* g2  = (const float*)d_in[11];
  const float* be2 = (const float*)d_in[12];

  char* ws = (char*)d_ws;
  size_t off = 0;
  u16* Wqkv = (u16*)(ws + off); off += (size_t)3072 * 1024 * 2;
  u16* Wob  = (u16*)(ws + off); off += (size_t)1024 * 1024 * 2;
  u16* W1T  = (u16*)(ws + off); off += (size_t)4096 * 1024 * 2;
  u16* W2T  = (u16*)(ws + off); off += (size_t)1024 * 4096 * 2;
  u16* Hb   = (u16*)(ws + off); off += (size_t)BT * 1024 * 2;
  u16* QKV  = (u16*)(ws + off); off += (size_t)BT * 3072 * 2;
  u16* AttO = (u16*)(ws + off); off += (size_t)BT * 1024 * 2;
  float* X2 = (float*)(ws + off); off += (size_t)BT * 1024 * 4;
  u16* FF1 = QKV;        // [8192][4096] overlays QKV+AttO exactly (both dead by then)
  u16* VT  = (u16*)X2;   // 16.8MB <= 32MB; dead before X2 is written (Wo GEMM)
  if (ws_size < off) return;
  const int KBIG = 1 << 20;  // kdiv for non-split calls

  // fused prep: Wq/Wk/Wv/Wo cvt + W1/W2 transpose + LN1, one launch
  prep_kernel<<<20480, 256, 0, stream>>>(Wq, Wk, Wv, Wo, W1, W2, x, g1, be1,
                                         Wqkv, W1T, W2T, Hb);
  gemm256<4, false><<<32 * 12, 512, 0, stream>>>(Hb, Wqkv, QKV, nullptr, nullptr, VT,
                                                 3072, 1024, 1024, 12, KBIG);
  attn_kernel<<<1024, 256, 0, stream>>>(QKV, VT, AttO);
  gemm256<1, false><<<32 * 4, 512, 0, stream>>>(AttO, Wob, X2, nullptr, x, nullptr,
                                                1024, 1024, 1024, 4, KBIG);
  ln_kernel<<<BT, 256, 0, stream>>>(X2, g2, be2, Hb);
  // FF1: persistent M-paired blocks (2 full pipelines, shared B-panel), grid 256
  gemm256<2, true><<<256, 512, 0, stream>>>(Hb, W1T, FF1, b1, nullptr, nullptr,
                                            4096, 1024, 1024, 16, KBIG);
  // FF2 split-K x2: full-chip grid 256; bf16 partials into dead Hb/AttO
  gemm256<0, false><<<32 * 8, 512, 0, stream>>>(FF1, W2T, Hb, nullptr, nullptr, AttO,
                                                1024, 2048, 4096, 4, 128);
  rf2_kernel<<<BT, 256, 0, stream>>>(Hb, AttO, b2, X2, (float*)d_out);
}